// Round 9
// baseline (195.442 us; speedup 1.0000x reference)
//
#include <hip/hip_runtime.h>

#define BATCH 4
#define SEQ   4096
#define EMB   512
#define HD    64

typedef __attribute__((ext_vector_type(8))) short short8;
typedef __attribute__((ext_vector_type(4))) float floatx4;

static __device__ __forceinline__ unsigned short f2bf(float f) {
  unsigned u = __builtin_bit_cast(unsigned, f);
  u += 0x7fffu + ((u >> 16) & 1u);           // round-to-nearest-even
  return (unsigned short)(u >> 16);
}
static __device__ __forceinline__ float bf2f(unsigned short h) {
  unsigned u = ((unsigned)h) << 16;
  return __builtin_bit_cast(float, u);
}
static __device__ __forceinline__ unsigned pack_hi16(float lo, float hi) {
#if __has_builtin(__builtin_amdgcn_perm)
  return __builtin_amdgcn_perm(__builtin_bit_cast(unsigned, hi),
                               __builtin_bit_cast(unsigned, lo), 0x07060302u);
#else
  return (__builtin_bit_cast(unsigned, lo) >> 16) |
         (__builtin_bit_cast(unsigned, hi) & 0xffff0000u);
#endif
}
static __device__ __forceinline__ unsigned pack_f16(float a, float b) {
#if __has_builtin(__builtin_amdgcn_cvt_pkrtz)
  typedef __fp16 fp16v2 __attribute__((ext_vector_type(2)));
  fp16v2 h = __builtin_amdgcn_cvt_pkrtz(a, b);
  return __builtin_bit_cast(unsigned, h);
#else
  _Float16 ha = (_Float16)a, hb = (_Float16)b;
  return (unsigned)__builtin_bit_cast(unsigned short, ha) |
         ((unsigned)__builtin_bit_cast(unsigned short, hb) << 16);
#endif
}
static __device__ __forceinline__ float f16_to_f32(unsigned short bits) {
  _Float16 h = __builtin_bit_cast(_Float16, bits);
  return (float)h;
}

#define CPSCALE 0.18033688011112042f   // (1/sqrt(64)) * log2(e)

// ---------------------------------------------------------------------------
// Kernel 0: pack W into MFMA fragment order, bf16; WQ pre-scaled by CPSCALE
// so flash scores land directly in the exp2 domain.  (unchanged from R8)
// ---------------------------------------------------------------------------
__global__ __launch_bounds__(256) void convw_kernel(
    const float* __restrict__ WQ, const float* __restrict__ WK,
    const float* __restrict__ WV, unsigned short* __restrict__ Wpk)
{
  int t = blockIdx.x * 256 + threadIdx.x;     // 0..16383
  int p    = t >> 12;
  int w    = (t >> 10) & 3;
  int kc   = (t >> 6) & 15;
  int lane = t & 63;
  int lr = lane & 15, g = lane >> 4;
  const float* src = (p == 0) ? WQ : ((p == 1) ? WK : WV);
  const float4* s4 = (const float4*)(src + (16 * w + lr) * EMB + kc * 32 + 8 * g);
  float4 a = s4[0], b = s4[1];
  float vv[8] = {a.x, a.y, a.z, a.w, b.x, b.y, b.z, b.w};
  const float sc = (p == 0) ? CPSCALE : 1.0f;
  short8 o;
#pragma unroll
  for (int j = 0; j < 8; ++j) {
    float v = vv[j] * sc;
    unsigned short h = f2bf(v);
    o[j] = (p == 3) ? (short)f2bf(v - bf2f(h)) : (short)h;
  }
  *(short8*)(Wpk + (size_t)t * 8) = o;
}

// ---------------------------------------------------------------------------
// Kernel 1: QKV projection — zero LDS/barriers, 16 rows/block, grid 1024.
// (unchanged from R8)
// ---------------------------------------------------------------------------
__global__ __launch_bounds__(256) void proj_kernel(
    const float* __restrict__ x,
    const unsigned short* __restrict__ Wpk,
    unsigned short* __restrict__ Qb,
    unsigned short* __restrict__ Kb,
    unsigned short* __restrict__ VTb)
{
  const int tid  = threadIdx.x;
  const int lane = tid & 63;
  const int w    = tid >> 6;
  const int lr   = lane & 15, g = lane >> 4;
  const long rowBase = (long)blockIdx.x * 16;

  const float* xp = x + (rowBase + lr) * EMB + 8 * g;
  const unsigned short* const wb0 = Wpk + (size_t)(w * 16) * 512 + lane * 8;

  floatx4 accQ = {0.f,0.f,0.f,0.f}, accK = accQ, accV = accQ;

#pragma unroll 4
  for (int kc = 0; kc < 16; ++kc) {
    const unsigned short* wb = wb0 + kc * 512;
    short8 wq  = *(const short8*)(wb);
    short8 wk  = *(const short8*)(wb + 32768);
    short8 wvh = *(const short8*)(wb + 2 * 32768);
    short8 wvl = *(const short8*)(wb + 3 * 32768);
    const float4* p = (const float4*)(xp + kc * 32);
    float4 a = p[0], b = p[1];
    float vv[8] = {a.x, a.y, a.z, a.w, b.x, b.y, b.z, b.w};
    short8 xh, xl;
#pragma unroll
    for (int i = 0; i < 8; ++i) {
      unsigned short h = f2bf(vv[i]);
      xh[i] = (short)h;
      xl[i] = (short)f2bf(vv[i] - bf2f(h));
    }
    accQ = __builtin_amdgcn_mfma_f32_16x16x32_bf16(wq, xh, accQ, 0, 0, 0);
    accK = __builtin_amdgcn_mfma_f32_16x16x32_bf16(wk, xh, accK, 0, 0, 0);
    accV = __builtin_amdgcn_mfma_f32_16x16x32_bf16(xh, wvh, accV, 0, 0, 0);
    accV = __builtin_amdgcn_mfma_f32_16x16x32_bf16(xl, wvh, accV, 0, 0, 0);
    accV = __builtin_amdgcn_mfma_f32_16x16x32_bf16(xh, wvl, accV, 0, 0, 0);
  }

  const int bb  = (int)(rowBase >> 12);
  const int sIn = (int)(rowBase & 4095);
  {
    long row = rowBase + lr;
    int  col = 16 * w + 4 * g;
    ushort4 u; u.x = f2bf(accQ[0]); u.y = f2bf(accQ[1]);
    u.z = f2bf(accQ[2]); u.w = f2bf(accQ[3]);
    *(ushort4*)(Qb + row * HD + col) = u;
    ushort4 v; v.x = f2bf(accK[0]); v.y = f2bf(accK[1]);
    v.z = f2bf(accK[2]); v.w = f2bf(accK[3]);
    *(ushort4*)(Kb + row * HD + col) = v;
  }
  {
    long addr = ((long)(bb * 64 + 16 * w + lr)) * SEQ + sIn + 4 * g;
    ushort4 u; u.x = f2bf(accV[0]); u.y = f2bf(accV[1]);
    u.z = f2bf(accV[2]); u.w = f2bf(accV[3]);
    *(ushort4*)(VTb + addr) = u;
  }
}

// ---------------------------------------------------------------------------
// Kernel 2 (R9): flash attention. Split-K x8 (512 blocks), q=64/wave,
// DOUBLE-BUFFERED K/V (restored — R8 proved single-buffer serialization
// costs ~12 us), exp2-direct (cp folded into WQ), ones-MFMA for l.
// Plds HALVED (qh processed in pairs): LDS 32+18.4 = 50.4 KB -> 3 blocks/CU
// = 12 waves/CU (R6 had 2 blocks/CU at 69.6 KB).
// ---------------------------------------------------------------------------
#define PST 72   // P row stride in shorts: 144 B

__global__ __launch_bounds__(256, 3) void flash_kernel(
    const unsigned short* __restrict__ Qb,
    const unsigned short* __restrict__ Kb,
    const unsigned short* __restrict__ VTb,
    unsigned short* __restrict__ Opart,   // fp16 bits [64*8][256][64]
    float* __restrict__ Lpart)            // [64*8][256]
{
  __shared__ __align__(16) unsigned short K0lds[64 * 64];
  __shared__ __align__(16) unsigned short V0lds[64 * 64];
  __shared__ __align__(16) unsigned short K1lds[64 * 64];
  __shared__ __align__(16) unsigned short V1lds[64 * 64];
  __shared__ __align__(16) unsigned short Plds[4][32 * PST];   // halved: qh-pairs

  const int tid  = threadIdx.x;
  const int lane = tid & 63;
  const int w    = tid >> 6;
  const int lr   = lane & 15, g = lane >> 4;
  const int qb   = blockIdx.x >> 3;      // 0..63 (256 q rows each)
  const int ks   = blockIdx.x & 7;       // K split
  const int bb   = qb >> 4;              // batch
  const long qrow0 = (long)qb * 256 + 64 * w;
  const int  kbase = ks * 512;

  const int koff0 = lr * 64 + 8 * ((    g) ^ (lr & 7));
  const int koff1 = lr * 64 + 8 * ((4 + g) ^ (lr & 7));
  const int voff0 = koff0, voff1 = koff1;
  const int pwoff = lr * PST + 4 * g;
  const int proff = lr * PST + 8 * g;
  unsigned short* const pw = &Plds[w][0];

  const int ci0  = tid;
  const int row0 = ci0 >> 3,        cc0 = (ci0 & 7) ^ (row0 & 7);
  const int ci1  = 256 + tid;
  const int row1 = ci1 >> 3,        cc1 = (ci1 & 7) ^ (row1 & 7);
  const unsigned short* const gK0 = Kb  + ((long)bb * SEQ + kbase + row0) * HD + cc0 * 8;
  const unsigned short* const gK1 = Kb  + ((long)bb * SEQ + kbase + row1) * HD + cc1 * 8;
  const unsigned short* const gV0 = VTb + ((long)bb * HD + row0) * SEQ + kbase + cc0 * 8;
  const unsigned short* const gV1 = VTb + ((long)bb * HD + row1) * SEQ + kbase + cc1 * 8;

  short8 qf[4][2];
#pragma unroll
  for (int qh = 0; qh < 4; ++qh)
#pragma unroll
    for (int ec = 0; ec < 2; ++ec)
      qf[qh][ec] = *(const short8*)(Qb + (qrow0 + 16 * qh + lr) * HD + ec * 32 + 8 * g);

  short8 onesb;
#pragma unroll
  for (int j = 0; j < 8; ++j) onesb[j] = (short)0x3F80;   // bf16 1.0

  floatx4 accO[4][4], accL[4];
#pragma unroll
  for (int qh = 0; qh < 4; ++qh) {
    floatx4 z = {0.f,0.f,0.f,0.f};
    accL[qh] = z;
#pragma unroll
    for (int t = 0; t < 4; ++t) accO[qh][t] = z;
  }

#define STAGE(kt_, KL, VL) do {                                               \
    const int ko_ = (kt_) * 64;                                               \
    __builtin_amdgcn_global_load_lds(                                         \
        (const __attribute__((address_space(1))) void*)(gK0 + (long)ko_ * HD),\
        (__attribute__((address_space(3))) void*)((KL) + ci0 * 8), 16, 0, 0); \
    __builtin_amdgcn_global_load_lds(                                         \
        (const __attribute__((address_space(1))) void*)(gV0 + ko_),           \
        (__attribute__((address_space(3))) void*)((VL) + ci0 * 8), 16, 0, 0); \
    __builtin_amdgcn_global_load_lds(                                         \
        (const __attribute__((address_space(1))) void*)(gK1 + (long)ko_ * HD),\
        (__attribute__((address_space(3))) void*)((KL) + ci1 * 8), 16, 0, 0); \
    __builtin_amdgcn_global_load_lds(                                         \
        (const __attribute__((address_space(1))) void*)(gV1 + ko_),           \
        (__attribute__((address_space(3))) void*)((VL) + ci1 * 8), 16, 0, 0); \
  } while (0)

#define COMPUTE(KL, VL) do {                                                  \
    short8 kf[2][4], vf[2][4];                                                \
    _Pragma("unroll")                                                         \
    for (int t = 0; t < 4; ++t) {                                             \
      kf[0][t] = *(const short8*)((KL) + koff0 + t * 1024);                   \
      kf[1][t] = *(const short8*)((KL) + koff1 + t * 1024);                   \
      vf[0][t] = *(const short8*)((VL) + voff0 + t * 1024);                   \
      vf[1][t] = *(const short8*)((VL) + voff1 + t * 1024);                   \
    }                                                                         \
    _Pragma("unroll")                                                         \
    for (int qp = 0; qp < 2; ++qp) {                                          \
      _Pragma("unroll")                                                       \
      for (int qi = 0; qi < 2; ++qi) {                                        \
        const int qh = 2 * qp + qi;                                           \
        floatx4 s_[4];                                                        \
        _Pragma("unroll")                                                     \
        for (int t = 0; t < 4; ++t) { floatx4 z = {0.f,0.f,0.f,0.f}; s_[t] = z; } \
        _Pragma("unroll")                                                     \
        for (int ec = 0; ec < 2; ++ec)                                        \
          _Pragma("unroll")                                                   \
          for (int t = 0; t < 4; ++t)                                         \
            s_[t] = __builtin_amdgcn_mfma_f32_16x16x32_bf16(kf[ec][t], qf[qh][ec], s_[t], 0, 0, 0); \
        _Pragma("unroll")                                                     \
        for (int t = 0; t < 4; ++t) {                                         \
          float p0 = __builtin_amdgcn_exp2f(s_[t][0]);                        \
          float p1 = __builtin_amdgcn_exp2f(s_[t][1]);                        \
          float p2 = __builtin_amdgcn_exp2f(s_[t][2]);                        \
          float p3 = __builtin_amdgcn_exp2f(s_[t][3]);                        \
          uint2 u;                                                            \
          u.x = pack_hi16(p0, p1);                                            \
          u.y = pack_hi16(p2, p3);                                            \
          *(uint2*)(pw + pwoff + qi * (16 * PST) + t * 16) = u;               \
        }                                                                     \
      }                                                                       \
      _Pragma("unroll")                                                       \
      for (int qi = 0; qi < 2; ++qi) {                                        \
        const int qh = 2 * qp + qi;                                           \
        _Pragma("unroll")                                                     \
        for (int c = 0; c < 2; ++c) {                                         \
          short8 pf = *(const short8*)(pw + proff + qi * (16 * PST) + c * 32);\
          accL[qh] = __builtin_amdgcn_mfma_f32_16x16x32_bf16(onesb, pf, accL[qh], 0, 0, 0); \
          _Pragma("unroll")                                                   \
          for (int t = 0; t < 4; ++t)                                         \
            accO[qh][t] = __builtin_amdgcn_mfma_f32_16x16x32_bf16(vf[c][t], pf, accO[qh][t], 0, 0, 0); \
        }                                                                     \
      }                                                                       \
    }                                                                         \
  } while (0)

  STAGE(0, K0lds, V0lds);
  for (int kt = 0; kt < 8; kt += 2) {
    __syncthreads();                       // drains tile kt loads (buf0)
    STAGE(kt + 1, K1lds, V1lds);           // prefetch next into buf1
    COMPUTE(K0lds, V0lds);
    __syncthreads();                       // drains tile kt+1 loads (buf1)
    if (kt + 2 < 8) STAGE(kt + 2, K0lds, V0lds);
    COMPUTE(K1lds, V1lds);
  }
#undef STAGE
#undef COMPUTE

  unsigned short* obase = Opart + (size_t)(qb * 8 + ks) * 256 * HD;
#pragma unroll
  for (int qh = 0; qh < 4; ++qh) {
    int qlocal = 64 * w + 16 * qh + lr;
#pragma unroll
    for (int t = 0; t < 4; ++t) {
      uint2 u;
      u.x = pack_f16(accO[qh][t][0], accO[qh][t][1]);
      u.y = pack_f16(accO[qh][t][2], accO[qh][t][3]);
      *(uint2*)(obase + qlocal * HD + 16 * t + 4 * g) = u;
    }
    if (g == 0) Lpart[(qb * 8 + ks) * 256 + qlocal] = accL[qh][0];
  }
}

// ---------------------------------------------------------------------------
// Kernel 3 (R9): combine split-K x8 partials. Lpart loads deduped: each
// 16-lane row-group loads the 8 L values twice (lane&7) and reduces with
// 3 shfl_xor (stays within the 8-lane subgroup) instead of 8 loads/lane.
// ---------------------------------------------------------------------------
__global__ __launch_bounds__(256) void combine_kernel(
    const unsigned short* __restrict__ Opart, const float* __restrict__ Lpart,
    float* __restrict__ out)
{
  int t   = blockIdx.x * 256 + threadIdx.x;
  int row = t >> 4;                            // global q row 0..16383
  int d0  = (t & 15) * 4;
  int qb = row >> 8, qi = row & 255;

  float lp = Lpart[(qb * 8 + (threadIdx.x & 7)) * 256 + qi];
  lp += __shfl_xor(lp, 1, 64);
  lp += __shfl_xor(lp, 2, 64);
  lp += __shfl_xor(lp, 4, 64);                 // lt replicated in all 8 lanes

  float4 acc = {0.f, 0.f, 0.f, 0.f};
#pragma unroll
  for (int ks = 0; ks < 8; ++ks) {
    const unsigned short* p = Opart + ((size_t)(qb * 8 + ks) * 256 + qi) * HD + d0;
    ushort4 v = *(const ushort4*)p;
    acc.x += f16_to_f32(v.x);
    acc.y += f16_to_f32(v.y);
    acc.z += f16_to_f32(v.z);
    acc.w += f16_to_f32(v.w);
  }
  float inv = 1.0f / lp;
  float4 o = {acc.x * inv, acc.y * inv, acc.z * inv, acc.w * inv};
  *(float4*)(out + (size_t)row * HD + d0) = o;
}

extern "C" void kernel_launch(void* const* d_in, const int* in_sizes, int n_in,
                              void* d_out, int out_size, void* d_ws, size_t ws_size,
                              hipStream_t stream) {
  const float* x  = (const float*)d_in[0];
  const float* WQ = (const float*)d_in[1];
  const float* WK = (const float*)d_in[2];
  const float* WV = (const float*)d_in[3];

  unsigned short* Qb  = (unsigned short*)d_ws;                  // [16384][64] bf16
  unsigned short* Kb  = Qb  + (size_t)BATCH * SEQ * HD;         // [16384][64] bf16
  unsigned short* VTb = Kb  + (size_t)BATCH * SEQ * HD;         // [4][64][4096] bf16
  unsigned short* Wpk = VTb + (size_t)BATCH * SEQ * HD;         // 262144 shorts
  unsigned short* Opart = Wpk + 262144;                         // fp16 [512][256][64]
  float* Lpart = (float*)(Opart + (size_t)512 * 256 * HD);      // [512][256] f32

  convw_kernel<<<64, 256, 0, stream>>>(WQ, WK, WV, Wpk);
  proj_kernel<<<(BATCH * SEQ) / 16, 256, 0, stream>>>(x, Wpk, Qb, Kb, VTb);
  flash_kernel<<<512, 256, 0, stream>>>(Qb, Kb, VTb, Opart, Lpart);
  combine_kernel<<<1024, 256, 0, stream>>>(Opart, Lpart, (float*)d_out);
}

// Round 10
// 119.634 us; speedup vs baseline: 1.6337x; 1.6337x over previous
//
#include <hip/hip_runtime.h>

#define BATCH 4
#define SEQ   4096
#define EMB   512
#define HD    64

typedef __attribute__((ext_vector_type(8))) short short8;
typedef __attribute__((ext_vector_type(4))) float floatx4;

static __device__ __forceinline__ unsigned short f2bf(float f) {
  unsigned u = __builtin_bit_cast(unsigned, f);
  u += 0x7fffu + ((u >> 16) & 1u);           // round-to-nearest-even
  return (unsigned short)(u >> 16);
}
static __device__ __forceinline__ float bf2f(unsigned short h) {
  unsigned u = ((unsigned)h) << 16;
  return __builtin_bit_cast(float, u);
}
static __device__ __forceinline__ unsigned pack_hi16(float lo, float hi) {
#if __has_builtin(__builtin_amdgcn_perm)
  return __builtin_amdgcn_perm(__builtin_bit_cast(unsigned, hi),
                               __builtin_bit_cast(unsigned, lo), 0x07060302u);
#else
  return (__builtin_bit_cast(unsigned, lo) >> 16) |
         (__builtin_bit_cast(unsigned, hi) & 0xffff0000u);
#endif
}
static __device__ __forceinline__ unsigned pack_f16(float a, float b) {
#if __has_builtin(__builtin_amdgcn_cvt_pkrtz)
  typedef __fp16 fp16v2 __attribute__((ext_vector_type(2)));
  fp16v2 h = __builtin_amdgcn_cvt_pkrtz(a, b);
  return __builtin_bit_cast(unsigned, h);
#else
  _Float16 ha = (_Float16)a, hb = (_Float16)b;
  return (unsigned)__builtin_bit_cast(unsigned short, ha) |
         ((unsigned)__builtin_bit_cast(unsigned short, hb) << 16);
#endif
}
static __device__ __forceinline__ float f16_to_f32(unsigned short bits) {
  _Float16 h = __builtin_bit_cast(_Float16, bits);
  return (float)h;
}

// ---------------------------------------------------------------------------
// Kernel 0: pack W into MFMA fragment order, bf16.
// Wpk[(((p*4+w)*16+kc)*64 + lane)*8 + j] = plane_p[16w+(lane&15)][kc*32+8*(lane>>4)+j]
// p: 0=WQ hi, 1=WK hi, 2=WV hi, 3=WV lo.
// ---------------------------------------------------------------------------
__global__ __launch_bounds__(256) void convw_kernel(
    const float* __restrict__ WQ, const float* __restrict__ WK,
    const float* __restrict__ WV, unsigned short* __restrict__ Wpk)
{
  int t = blockIdx.x * 256 + threadIdx.x;     // 0..16383
  int p    = t >> 12;
  int w    = (t >> 10) & 3;
  int kc   = (t >> 6) & 15;
  int lane = t & 63;
  int lr = lane & 15, g = lane >> 4;
  const float* src = (p == 0) ? WQ : ((p == 1) ? WK : WV);
  const float4* s4 = (const float4*)(src + (16 * w + lr) * EMB + kc * 32 + 8 * g);
  float4 a = s4[0], b = s4[1];
  float vv[8] = {a.x, a.y, a.z, a.w, b.x, b.y, b.z, b.w};
  short8 o;
#pragma unroll
  for (int j = 0; j < 8; ++j) {
    unsigned short h = f2bf(vv[j]);
    o[j] = (p == 3) ? (short)f2bf(vv[j] - bf2f(h)) : (short)h;
  }
  *(short8*)(Wpk + (size_t)t * 8) = o;
}

// ---------------------------------------------------------------------------
// Kernel 1: QKV projection, software-pipelined. 32 rows/block, grid 512.
// x loaded to regs at distance 2; split+LDS-write happens AFTER compute so
// the wave never stalls on a cold HBM load before issuing MFMAs.
// ---------------------------------------------------------------------------
#define XST 40   // LDS x row stride in shorts: 80 B (16B-mult, 2-way banks = free)

__global__ __launch_bounds__(256) void proj_kernel(
    const float* __restrict__ x,
    const unsigned short* __restrict__ Wpk,
    unsigned short* __restrict__ Qb,
    unsigned short* __restrict__ Kb,
    unsigned short* __restrict__ VTb)
{
  __shared__ __align__(16) unsigned short Xh[2][32 * XST];
  __shared__ __align__(16) unsigned short Xl[2][32 * XST];

  const int tid  = threadIdx.x;
  const int lane = tid & 63;
  const int w    = tid >> 6;
  const int lr   = lane & 15, g = lane >> 4;
  const long rowBase = (long)blockIdx.x * 32;

  floatx4 accQ[2], accK[2], accV[2];
#pragma unroll
  for (int rt = 0; rt < 2; ++rt) {
    floatx4 z = {0.f, 0.f, 0.f, 0.f};
    accQ[rt] = z; accK[rt] = z; accV[rt] = z;
  }

  const int srow = tid >> 3;          // 0..31
  const int sc   = 4 * (tid & 7);     // 0,4,..,28
  const float* xbase = x + (rowBase + srow) * EMB + sc;

  auto stage_write = [&](float4 v, int buf) {
    float vv[4] = {v.x, v.y, v.z, v.w};
    ushort4 hi, lo;
#pragma unroll
    for (int i = 0; i < 4; ++i) {
      unsigned short h = f2bf(vv[i]);
      ((unsigned short*)&hi)[i] = h;
      ((unsigned short*)&lo)[i] = f2bf(vv[i] - bf2f(h));
    }
    *(ushort4*)&Xh[buf][srow * XST + sc] = hi;
    *(ushort4*)&Xl[buf][srow * XST + sc] = lo;
  };

  float4 xv = *(const float4*)(xbase);          // kc=0
  stage_write(xv, 0);
  float4 xnxt = *(const float4*)(xbase + 32);   // kc=1

#pragma unroll 2
  for (int kc = 0; kc < 16; ++kc) {
    __syncthreads();                            // buf[kc&1] ready for all
    // issue W loads for this kc (L2-hot, coalesced 1 KB/wave each)
    const unsigned short* wb = Wpk + (size_t)(w * 16 + kc) * 512 + lane * 8;
    short8 wq  = *(const short8*)(wb);
    short8 wk  = *(const short8*)(wb + 32768);
    short8 wvh = *(const short8*)(wb + 2 * 32768);
    short8 wvl = *(const short8*)(wb + 3 * 32768);
    // issue x load for kc+2 (consumed at end of NEXT iteration)
    float4 xfut;
    if (kc + 2 < 16) xfut = *(const float4*)(xbase + (kc + 2) * 32);
    const int buf = kc & 1;
#pragma unroll
    for (int rt = 0; rt < 2; ++rt) {
      short8 xh = *(const short8*)&Xh[buf][(16 * rt + lr) * XST + 8 * g];
      short8 xl = *(const short8*)&Xl[buf][(16 * rt + lr) * XST + 8 * g];
      accQ[rt] = __builtin_amdgcn_mfma_f32_16x16x32_bf16(wq, xh, accQ[rt], 0, 0, 0);
      accK[rt] = __builtin_amdgcn_mfma_f32_16x16x32_bf16(wk, xh, accK[rt], 0, 0, 0);
      accV[rt] = __builtin_amdgcn_mfma_f32_16x16x32_bf16(xh, wvh, accV[rt], 0, 0, 0);
      accV[rt] = __builtin_amdgcn_mfma_f32_16x16x32_bf16(xl, wvh, accV[rt], 0, 0, 0);
      accV[rt] = __builtin_amdgcn_mfma_f32_16x16x32_bf16(xh, wvl, accV[rt], 0, 0, 0);
    }
    // stage kc+1 into the other buffer (safe: its last readers finished
    // before the barrier at the top of this iteration)
    if (kc + 1 < 16) { stage_write(xnxt, (kc + 1) & 1); xnxt = xfut; }
  }

  // C layout: col(n) = lane&15, row(m) = 4*(lane>>4)+reg
  const int bb  = (int)(rowBase >> 12);
  const int sIn = (int)(rowBase & 4095);
#pragma unroll
  for (int rt = 0; rt < 2; ++rt) {
    {  // Q,K: D[m=outcol][n=xrow]: row = rowBase+16rt+lr, col = 16w+4g+r
      long row = rowBase + 16 * rt + lr;
      int  col = 16 * w + 4 * g;
      ushort4 u; u.x = f2bf(accQ[rt][0]); u.y = f2bf(accQ[rt][1]);
      u.z = f2bf(accQ[rt][2]); u.w = f2bf(accQ[rt][3]);
      *(ushort4*)(Qb + row * HD + col) = u;
      ushort4 v; v.x = f2bf(accK[rt][0]); v.y = f2bf(accK[rt][1]);
      v.z = f2bf(accK[rt][2]); v.w = f2bf(accK[rt][3]);
      *(ushort4*)(Kb + row * HD + col) = v;
    }
    {  // V: D[m=xrow][n=vcol]: d = 16w+lr, s = rowBase+16rt+4g+r
      long addr = ((long)(bb * 64 + 16 * w + lr)) * SEQ + sIn + 16 * rt + 4 * g;
      ushort4 u; u.x = f2bf(accV[rt][0]); u.y = f2bf(accV[rt][1]);
      u.z = f2bf(accV[rt][2]); u.w = f2bf(accV[rt][3]);
      *(ushort4*)(VTb + addr) = u;
    }
  }
}

// ---------------------------------------------------------------------------
// Kernel 2: flash attention. q=64/wave (256 q/block), split-K x8 (512 keys =
// 8 tiles of 64 per block), grid 512 = 2 blocks/CU. K-frags and V-frags are
// register-cached once per tile and reused across the 4 q-halves. Fixed-shift
// softmax (exact), split partials sum-combinable.
// ---------------------------------------------------------------------------
#define PST 72   // P row stride in shorts: 144 B

__global__ __launch_bounds__(256, 2) void flash_kernel(
    const unsigned short* __restrict__ Qb,
    const unsigned short* __restrict__ Kb,
    const unsigned short* __restrict__ VTb,
    unsigned short* __restrict__ Opart,   // fp16 bits [64*8][256][64]
    float* __restrict__ Lpart)            // [64*8][256]
{
  __shared__ __align__(16) unsigned short K0lds[64 * 64];
  __shared__ __align__(16) unsigned short V0lds[64 * 64];
  __shared__ __align__(16) unsigned short K1lds[64 * 64];
  __shared__ __align__(16) unsigned short V1lds[64 * 64];
  __shared__ __align__(16) unsigned short Plds[4][64 * PST];

  const int tid  = threadIdx.x;
  const int lane = tid & 63;
  const int w    = tid >> 6;
  const int lr   = lane & 15, g = lane >> 4;
  const int qb   = blockIdx.x >> 3;      // 0..63 (256 q rows each, linear)
  const int ks   = blockIdx.x & 7;       // K split (XCD-pinned)
  const int bb   = qb >> 4;              // batch
  const long qrow0 = (long)qb * 256 + 64 * w;   // wave's global q base row
  const int  kbase = ks * 512;

  short8 qf[4][2];
#pragma unroll
  for (int qh = 0; qh < 4; ++qh)
#pragma unroll
    for (int ec = 0; ec < 2; ++ec)
      qf[qh][ec] = *(const short8*)(Qb + (qrow0 + 16 * qh + lr) * HD + ec * 32 + 8 * g);

  floatx4 accO[4][4];
#pragma unroll
  for (int qh = 0; qh < 4; ++qh)
#pragma unroll
    for (int t = 0; t < 4; ++t) { floatx4 z = {0.f,0.f,0.f,0.f}; accO[qh][t] = z; }
  float lsum[4] = {0.f, 0.f, 0.f, 0.f};
  const float cp = 0.18033688011112042f;   // (1/sqrt(64)) * log2(e)
  const float SH = 2.0f;                   // fixed shift (exp2 domain), exact

#define STAGE(kt_, KL, VL) do {                                               \
    const int k0_ = kbase + (kt_) * 64;                                       \
    _Pragma("unroll")                                                         \
    for (int h_ = 0; h_ < 2; ++h_) {                                          \
      int ci_  = h_ * 256 + tid;                                              \
      int row_ = ci_ >> 3;                                                    \
      int cc_  = (ci_ & 7) ^ (row_ & 7);                                      \
      const unsigned short* gK_ = Kb + ((long)bb * SEQ + k0_ + row_) * HD + cc_ * 8; \
      __builtin_amdgcn_global_load_lds(                                       \
          (const __attribute__((address_space(1))) void*)gK_,                 \
          (__attribute__((address_space(3))) void*)((KL) + ci_ * 8), 16, 0, 0); \
      const unsigned short* gV_ = VTb + ((long)bb * HD + row_) * SEQ + k0_ + cc_ * 8; \
      __builtin_amdgcn_global_load_lds(                                       \
          (const __attribute__((address_space(1))) void*)gV_,                 \
          (__attribute__((address_space(3))) void*)((VL) + ci_ * 8), 16, 0, 0); \
    }                                                                         \
  } while (0)

#define COMPUTE(KL, VL) do {                                                  \
    short8 kf[2][4];                                                          \
    _Pragma("unroll")                                                         \
    for (int ec = 0; ec < 2; ++ec)                                            \
      _Pragma("unroll")                                                       \
      for (int t = 0; t < 4; ++t) {                                           \
        int key  = 16 * t + lr;                                               \
        int slot = key * 8 + ((4 * ec + g) ^ (key & 7));                      \
        kf[ec][t] = *(const short8*)((KL) + slot * 8);                        \
      }                                                                       \
    _Pragma("unroll")                                                         \
    for (int qh = 0; qh < 4; ++qh) {                                          \
      floatx4 s_[4];                                                          \
      _Pragma("unroll")                                                       \
      for (int t = 0; t < 4; ++t) { floatx4 z = {0.f,0.f,0.f,0.f}; s_[t] = z; } \
      _Pragma("unroll")                                                       \
      for (int ec = 0; ec < 2; ++ec)                                          \
        _Pragma("unroll")                                                     \
        for (int t = 0; t < 4; ++t)                                           \
          s_[t] = __builtin_amdgcn_mfma_f32_16x16x32_bf16(kf[ec][t], qf[qh][ec], s_[t], 0, 0, 0); \
      unsigned short* prow = &Plds[w][(16 * qh + lr) * PST];                  \
      float ls = 0.0f;                                                        \
      _Pragma("unroll")                                                       \
      for (int t = 0; t < 4; ++t) {                                           \
        float p0 = __builtin_amdgcn_exp2f(__builtin_fmaf(s_[t][0], cp, -SH)); \
        float p1 = __builtin_amdgcn_exp2f(__builtin_fmaf(s_[t][1], cp, -SH)); \
        float p2 = __builtin_amdgcn_exp2f(__builtin_fmaf(s_[t][2], cp, -SH)); \
        float p3 = __builtin_amdgcn_exp2f(__builtin_fmaf(s_[t][3], cp, -SH)); \
        uint2 u;                                                              \
        u.x = pack_hi16(p0, p1);                                              \
        u.y = pack_hi16(p2, p3);                                              \
        ls += __builtin_bit_cast(float, u.x << 16);                           \
        ls += __builtin_bit_cast(float, u.x & 0xffff0000u);                   \
        ls += __builtin_bit_cast(float, u.y << 16);                           \
        ls += __builtin_bit_cast(float, u.y & 0xffff0000u);                   \
        *(uint2*)(prow + 16 * t + 4 * g) = u;                                 \
      }                                                                       \
      lsum[qh] += ls;                                                         \
    }                                                                         \
    short8 vf[2][4];                                                          \
    _Pragma("unroll")                                                         \
    for (int c = 0; c < 2; ++c)                                               \
      _Pragma("unroll")                                                       \
      for (int t = 0; t < 4; ++t) {                                           \
        int d    = 16 * t + lr;                                               \
        int slot = d * 8 + ((4 * c + g) ^ (d & 7));                           \
        vf[c][t] = *(const short8*)((VL) + slot * 8);                         \
      }                                                                       \
    _Pragma("unroll")                                                         \
    for (int qh = 0; qh < 4; ++qh)                                            \
      _Pragma("unroll")                                                       \
      for (int c = 0; c < 2; ++c) {                                           \
        short8 pf = *(const short8*)(&Plds[w][(16 * qh + lr) * PST + 32 * c + 8 * g]); \
        _Pragma("unroll")                                                     \
        for (int t = 0; t < 4; ++t)                                           \
          accO[qh][t] = __builtin_amdgcn_mfma_f32_16x16x32_bf16(vf[c][t], pf, accO[qh][t], 0, 0, 0); \
      }                                                                       \
  } while (0)

  STAGE(0, K0lds, V0lds);
  for (int kt = 0; kt < 8; kt += 2) {
    __syncthreads();                       // drains tile kt loads (buf0)
    STAGE(kt + 1, K1lds, V1lds);           // prefetch next into buf1
    COMPUTE(K0lds, V0lds);
    __syncthreads();                       // drains tile kt+1 loads (buf1)
    if (kt + 2 < 8) STAGE(kt + 2, K0lds, V0lds);
    COMPUTE(K1lds, V1lds);
  }
#undef STAGE
#undef COMPUTE

  // epilogue: reduce l across g-groups; store fp16 O partials + fp32 l
  unsigned short* obase = Opart + (size_t)(qb * 8 + ks) * 256 * HD;
#pragma unroll
  for (int qh = 0; qh < 4; ++qh) {
    float l = lsum[qh];
    l += __shfl_xor(l, 16, 64);
    l += __shfl_xor(l, 32, 64);
    int qlocal = 64 * w + 16 * qh + lr;
#pragma unroll
    for (int t = 0; t < 4; ++t) {
      uint2 u;
      u.x = pack_f16(accO[qh][t][0], accO[qh][t][1]);
      u.y = pack_f16(accO[qh][t][2], accO[qh][t][3]);
      *(uint2*)(obase + qlocal * HD + 16 * t + 4 * g) = u;
    }
    if (g == 0) Lpart[(qb * 8 + ks) * 256 + qlocal] = l;
  }
}

// ---------------------------------------------------------------------------
// Kernel 3: combine split-K partials: out = sum_ks O_ks / sum_ks l_ks.
// ---------------------------------------------------------------------------
__global__ __launch_bounds__(256) void combine_kernel(
    const unsigned short* __restrict__ Opart, const float* __restrict__ Lpart,
    float* __restrict__ out)
{
  int t   = blockIdx.x * 256 + threadIdx.x;
  int row = t >> 4;                            // global q row 0..16383
  int d0  = (t & 15) * 4;
  int qb = row >> 8, qi = row & 255;
  float4 acc = {0.f, 0.f, 0.f, 0.f};
  float lt = 0.0f;
#pragma unroll
  for (int ks = 0; ks < 8; ++ks) {
    const unsigned short* p = Opart + ((size_t)(qb * 8 + ks) * 256 + qi) * HD + d0;
    ushort4 v = *(const ushort4*)p;
    acc.x += f16_to_f32(v.x);
    acc.y += f16_to_f32(v.y);
    acc.z += f16_to_f32(v.z);
    acc.w += f16_to_f32(v.w);
    lt += Lpart[(qb * 8 + ks) * 256 + qi];
  }
  float inv = 1.0f / lt;
  float4 o = {acc.x * inv, acc.y * inv, acc.z * inv, acc.w * inv};
  *(float4*)(out + (size_t)row * HD + d0) = o;
}

extern "C" void kernel_launch(void* const* d_in, const int* in_sizes, int n_in,
                              void* d_out, int out_size, void* d_ws, size_t ws_size,
                              hipStream_t stream) {
  const float* x  = (const float*)d_in[0];
  const float* WQ = (const float*)d_in[1];
  const float* WK = (const float*)d_in[2];
  const float* WV = (const float*)d_in[3];

  unsigned short* Qb  = (unsigned short*)d_ws;                  // [16384][64] bf16
  unsigned short* Kb  = Qb  + (size_t)BATCH * SEQ * HD;         // [16384][64] bf16
  unsigned short* VTb = Kb  + (size_t)BATCH * SEQ * HD;         // [4][64][4096] bf16
  unsigned short* Wpk = VTb + (size_t)BATCH * SEQ * HD;         // 262144 shorts
  unsigned short* Opart = Wpk + 262144;                         // fp16 [512][256][64]
  float* Lpart = (float*)(Opart + (size_t)512 * 256 * HD);      // [512][256] f32

  convw_kernel<<<64, 256, 0, stream>>>(WQ, WK, WV, Wpk);
  proj_kernel<<<(BATCH * SEQ) / 32, 256, 0, stream>>>(x, Wpk, Qb, Kb, VTb);
  flash_kernel<<<512, 256, 0, stream>>>(Qb, Kb, VTb, Opart, Lpart);
  combine_kernel<<<1024, 256, 0, stream>>>(Opart, Lpart, (float*)d_out);
}